// Round 4
// baseline (139.886 us; speedup 1.0000x reference)
//
#include <hip/hip_runtime.h>
#include <hip/hip_bf16.h>

// ProductLayer: B=4096, F=32, D=64, U=256
// out[:,   0:256] = lz       = E[B,2048] @ W1[2048,256]
// out[:, 256:512] = lp_inner = G[B,1024] @ V [1024,256]   (G_b = E_b E_b^T gram)
// out[:, 512:768] = lp_outer = M[B,4096] @ W2[4096,256]   (M_b = fs fs^T, rank-1,
//                              generated in-register from FS, never materialized)
// A  = [E | G] bf16 [4096, 3072]; FS = bf16 [4096, 64]; Wt = bf16 [256, 7168] (N-major)
// GEMM v4: wave-level, LDS-free, barrier-free. Wave = 16 rows x 64 cols, direct
// global->VGPR fragment loads, manual depth-1 prefetch. 768 blocks x 4 waves.

#define KA 3072
#define KW 7168

typedef __attribute__((ext_vector_type(8))) short short8v;
typedef __attribute__((ext_vector_type(4))) float f32x4;

union FragU { int i32[4]; short8v v; };

static __device__ __forceinline__ short f2bf(float f) {
    union { float f; unsigned u; } v; v.f = f;
    unsigned r = v.u + 0x7fffu + ((v.u >> 16) & 1u);  // RNE
    return (short)(r >> 16);
}
static __device__ __forceinline__ float bf2f(short s) {
    union { unsigned u; float f; } v; v.u = ((unsigned)(unsigned short)s) << 16;
    return v.f;
}
static __device__ __forceinline__ int cvtpk(float lo, float hi) {
    int r;
    asm("v_cvt_pk_bf16_f32 %0, %1, %2" : "=v"(r) : "v"(lo), "v"(hi));
    return r;
}

// ---------------- prep A: one block per batch row ----------------
__global__ __launch_bounds__(256) void prep_a(const float* __restrict__ embeds,
                                              short* __restrict__ A,
                                              short* __restrict__ FS) {
    int b = blockIdx.x;
    const float* e = embeds + (size_t)b * 2048;
    short* arow = A + (size_t)b * KA;
    __shared__ float se[2048];     // fp32 row [32][64]
    __shared__ short sebf[2048];   // bf16 row [32][64]
    int t = threadIdx.x;

    float4 v0 = ((const float4*)e)[t * 2];
    float4 v1 = ((const float4*)e)[t * 2 + 1];
    ((float4*)se)[t * 2] = v0;
    ((float4*)se)[t * 2 + 1] = v1;
    short8v sb;
    sb[0] = f2bf(v0.x); sb[1] = f2bf(v0.y); sb[2] = f2bf(v0.z); sb[3] = f2bf(v0.w);
    sb[4] = f2bf(v1.x); sb[5] = f2bf(v1.y); sb[6] = f2bf(v1.z); sb[7] = f2bf(v1.w);
    ((short8v*)sebf)[t] = sb;
    *(short8v*)&arow[t * 8] = sb;   // E segment [0, 2048)

    __syncthreads();
    if (t < 64) {
        float s = 0.f;
        #pragma unroll
        for (int f = 0; f < 32; ++f) s += se[f * 64 + t];
        FS[(size_t)b * 64 + t] = f2bf(s);
    }

    // G = E E^T via MFMA: 4 waves, one 16x16 tile each, K=64 in 2 steps
    int wid = t >> 6, lane = t & 63;
    int tm = wid >> 1, tn = wid & 1;
    int lr = lane & 15, lk = (lane >> 4) * 8;
    f32x4 g = {0.f, 0.f, 0.f, 0.f};
    #pragma unroll
    for (int ks = 0; ks < 2; ++ks) {
        short8v a  = *(const short8v*)&sebf[(tm * 16 + lr) * 64 + ks * 32 + lk];
        short8v bb = *(const short8v*)&sebf[(tn * 16 + lr) * 64 + ks * 32 + lk];
        g = __builtin_amdgcn_mfma_f32_16x16x32_bf16(a, bb, g, 0, 0, 0);
    }
    #pragma unroll
    for (int r = 0; r < 4; ++r) {
        int grow = tm * 16 + (lane >> 4) * 4 + r;  // C/D: col=lane&15, row=(lane>>4)*4+r
        int gcol = tn * 16 + lr;
        arow[2048 + grow * 32 + gcol] = f2bf(g[r]);  // G segment [2048, 3072)
    }
}

// ---------------- prep W: one block per unit u ----------------
__global__ __launch_bounds__(256) void prep_w(const float* __restrict__ lw,
                                              const float* __restrict__ iw,
                                              const float* __restrict__ ow,
                                              short* __restrict__ Wt) {
    int u = blockIdx.x;
    int t = threadIdx.x;
    short* w = Wt + (size_t)u * KW;

    for (int k = t; k < 2048; k += 256) w[k] = f2bf(lw[(size_t)k * 256 + u]);

    __shared__ float wi[32];
    if (t < 32) wi[t] = iw[u * 32 + t];
    __syncthreads();
    for (int idx = t; idx < 1024; idx += 256)
        w[2048 + idx] = f2bf(wi[idx >> 5] * wi[idx & 31]);

    const float* owu = ow + (size_t)u * 4096;
    for (int i = t; i < 512; i += 256) {
        float4 a = ((const float4*)owu)[i * 2];
        float4 b = ((const float4*)owu)[i * 2 + 1];
        short8v s;
        s[0] = f2bf(a.x); s[1] = f2bf(a.y); s[2] = f2bf(a.z); s[3] = f2bf(a.w);
        s[4] = f2bf(b.x); s[5] = f2bf(b.y); s[6] = f2bf(b.z); s[7] = f2bf(b.w);
        *(short8v*)&w[3072 + i * 8] = s;
    }
}

// ---------------- wave-level GEMM, direct loads, depth-1 prefetch ----------------
template<int NK>  // NK = K/32 steps; processed as NK/2 groups of 2
__device__ __forceinline__ void gemm_direct(const short* __restrict__ Ag,
                                            const short* __restrict__ Bg,
                                            f32x4 acc[4]) {
    short8v a0 = *(const short8v*)Ag;
    short8v a1 = *(const short8v*)(Ag + 32);
    short8v b0[4], b1[4];
    #pragma unroll
    for (int n = 0; n < 4; ++n) {
        b0[n] = *(const short8v*)(Bg + (size_t)n * 16 * KW);
        b1[n] = *(const short8v*)(Bg + (size_t)n * 16 * KW + 32);
    }
    #pragma unroll 2
    for (int g = 0; g < NK / 2; ++g) {
        short8v na0, na1, nb0[4], nb1[4];
        if (g + 1 < NK / 2) {
            const short* Ap = Ag + (g + 1) * 64;
            const short* Bp = Bg + (g + 1) * 64;
            na0 = *(const short8v*)Ap;
            na1 = *(const short8v*)(Ap + 32);
            #pragma unroll
            for (int n = 0; n < 4; ++n) {
                nb0[n] = *(const short8v*)(Bp + (size_t)n * 16 * KW);
                nb1[n] = *(const short8v*)(Bp + (size_t)n * 16 * KW + 32);
            }
        }
        #pragma unroll
        for (int n = 0; n < 4; ++n)
            acc[n] = __builtin_amdgcn_mfma_f32_16x16x32_bf16(a0, b0[n], acc[n], 0, 0, 0);
        #pragma unroll
        for (int n = 0; n < 4; ++n)
            acc[n] = __builtin_amdgcn_mfma_f32_16x16x32_bf16(a1, b1[n], acc[n], 0, 0, 0);
        a0 = na0; a1 = na1;
        #pragma unroll
        for (int n = 0; n < 4; ++n) { b0[n] = nb0[n]; b1[n] = nb1[n]; }
    }
}

// seg2: A-frags generated in-register from fs (M[r, i*64+j] = fs_r[i]*fs_r[j]).
// Lane's row = lr; per K=32 group g (steps 2g,2g+1): i = g, j-octet = lk8 (lo) / lk8+32 (hi).
__device__ __forceinline__ void gemm_gen(const short* __restrict__ fsrow,
                                         const short* __restrict__ Bg,
                                         int lk8, f32x4 acc[4]) {
    short8v lo = *(const short8v*)(fsrow + lk8);
    short8v hi = *(const short8v*)(fsrow + lk8 + 32);
    float fl[8], fh[8];
    #pragma unroll
    for (int j = 0; j < 8; ++j) { fl[j] = bf2f(lo[j]); fh[j] = bf2f(hi[j]); }
    float s = bf2f(fsrow[0]);
    short8v b0[4], b1[4];
    #pragma unroll
    for (int n = 0; n < 4; ++n) {
        b0[n] = *(const short8v*)(Bg + (size_t)n * 16 * KW);
        b1[n] = *(const short8v*)(Bg + (size_t)n * 16 * KW + 32);
    }
    #pragma unroll 2
    for (int g = 0; g < 64; ++g) {
        float ns; short8v nb0[4], nb1[4];
        if (g + 1 < 64) {
            ns = bf2f(fsrow[g + 1]);
            const short* Bp = Bg + (g + 1) * 64;
            #pragma unroll
            for (int n = 0; n < 4; ++n) {
                nb0[n] = *(const short8v*)(Bp + (size_t)n * 16 * KW);
                nb1[n] = *(const short8v*)(Bp + (size_t)n * 16 * KW + 32);
            }
        }
        FragU fa, fb;
        #pragma unroll
        for (int q = 0; q < 4; ++q) fa.i32[q] = cvtpk(s * fl[2 * q], s * fl[2 * q + 1]);
        #pragma unroll
        for (int q = 0; q < 4; ++q) fb.i32[q] = cvtpk(s * fh[2 * q], s * fh[2 * q + 1]);
        #pragma unroll
        for (int n = 0; n < 4; ++n)
            acc[n] = __builtin_amdgcn_mfma_f32_16x16x32_bf16(fa.v, b0[n], acc[n], 0, 0, 0);
        #pragma unroll
        for (int n = 0; n < 4; ++n)
            acc[n] = __builtin_amdgcn_mfma_f32_16x16x32_bf16(fb.v, b1[n], acc[n], 0, 0, 0);
        s = ns;
        #pragma unroll
        for (int n = 0; n < 4; ++n) { b0[n] = nb0[n]; b1[n] = nb1[n]; }
    }
}

// 768 blocks x 4 waves. id%3 interleaves segments (balance); wave owns 16 rows x 64 cols.
__global__ __launch_bounds__(256) void gemm_wave(const short* __restrict__ A,
                                                 const short* __restrict__ Wt,
                                                 const short* __restrict__ FS,
                                                 float* __restrict__ out) {
    int id = blockIdx.x;
    int s3 = id % 3;
    int rr = id / 3;                          // 0..255
    int seg = (s3 == 0) ? 2 : (s3 == 1) ? 0 : 1;
    int nt4 = rr & 3, mtb = rr >> 2;          // nt 0..3, mtb 0..63
    int wid = threadIdx.x >> 6, lane = threadIdx.x & 63;
    int mrow = (mtb * 4 + wid) * 16;
    int lr = lane & 15, lk8 = (lane >> 4) * 8;
    int bcol = nt4 * 64;
    int boff = (seg == 0) ? 0 : (seg == 1) ? 2048 : 3072;
    const short* Bg = Wt + (size_t)(bcol + lr) * KW + boff + lk8;

    f32x4 acc[4];
    #pragma unroll
    for (int n = 0; n < 4; ++n) acc[n] = (f32x4){0.f, 0.f, 0.f, 0.f};

    if (seg == 0)
        gemm_direct<64>(A + (size_t)(mrow + lr) * KA + lk8, Bg, acc);
    else if (seg == 1)
        gemm_direct<32>(A + (size_t)(mrow + lr) * KA + 2048 + lk8, Bg, acc);
    else
        gemm_gen(FS + (size_t)(mrow + lr) * 64, Bg, lk8, acc);

    int col0 = seg * 256 + bcol + lr;
    int row0 = mrow + (lane >> 4) * 4;
    #pragma unroll
    for (int n = 0; n < 4; ++n)
        #pragma unroll
        for (int r = 0; r < 4; ++r)
            out[(size_t)(row0 + r) * 768 + col0 + n * 16] = acc[n][r];
}

extern "C" void kernel_launch(void* const* d_in, const int* in_sizes, int n_in,
                              void* d_out, int out_size, void* d_ws, size_t ws_size,
                              hipStream_t stream) {
    const float* embeds = (const float*)d_in[0];
    const float* lw = (const float*)d_in[1];
    const float* iw = (const float*)d_in[2];
    const float* ow = (const float*)d_in[3];
    float* out = (float*)d_out;

    short* A  = (short*)d_ws;                    // 4096*3072*2 = 25,165,824 B
    short* Wt = A + (size_t)4096 * KA;           // + 256*7168*2 = 3,670,016 B
    short* FS = Wt + (size_t)256 * KW;           // + 4096*64*2 =    524,288 B

    prep_a<<<dim3(4096), dim3(256), 0, stream>>>(embeds, A, FS);
    prep_w<<<dim3(256), dim3(256), 0, stream>>>(lw, iw, ow, Wt);
    gemm_wave<<<dim3(768), dim3(256), 0, stream>>>(A, Wt, FS, out);
}

// Round 5
// 65.213 us; speedup vs baseline: 2.1450x; 2.1450x over previous
//
#include <hip/hip_runtime.h>
#include <hip/hip_bf16.h>

// ProductLayer: B=4096, F=32, D=64, U=256
// out[:,   0:256] = lz       = E[B,2048] @ W1[2048,256]
// out[:, 256:512] = lp_inner = G[B,1024] @ V [1024,256]   (G_b = E_b E_b^T gram)
// out[:, 512:768] = lp_outer = M[B,4096] @ W2[4096,256]   (M rank-1 from FS, in-register)
// A = [E | G] bf16 [4096, 3072]; FS bf16 [4096,64]; Wt bf16 [256, 7168] (N-major)
// GEMM v5: BM=256 BN=64 BK=64, wave=64x64 (m97 frag ratio), 512 blocks (2/CU),
// XOR-swizzled LDS (pre-swizzled global src + swizzled ds_read), dbuf stage-first
// pipeline, fp32 atomic epilogue into zeroed out.

#define KA 3072
#define KW 7168

typedef __attribute__((ext_vector_type(8))) short short8v;
typedef __attribute__((ext_vector_type(4))) float f32x4;

#define GLOAD(src, dst) __builtin_amdgcn_global_load_lds( \
    (const __attribute__((address_space(1))) void*)(src), \
    (__attribute__((address_space(3))) void*)(dst), 16, 0, 0)

static __device__ __forceinline__ short f2bf(float f) {
    union { float f; unsigned u; } v; v.f = f;
    unsigned r = v.u + 0x7fffu + ((v.u >> 16) & 1u);  // RNE
    return (short)(r >> 16);
}
static __device__ __forceinline__ float bf2f(short s) {
    union { unsigned u; float f; } v; v.u = ((unsigned)(unsigned short)s) << 16;
    return v.f;
}
static __device__ __forceinline__ int cvtpk(float lo, float hi) {
    int r;
    asm("v_cvt_pk_bf16_f32 %0, %1, %2" : "=v"(r) : "v"(lo), "v"(hi));
    return r;
}

// ---------------- prep A: one block per batch row ----------------
__global__ __launch_bounds__(256) void prep_a(const float* __restrict__ embeds,
                                              short* __restrict__ A,
                                              short* __restrict__ FS) {
    int b = blockIdx.x;
    const float* e = embeds + (size_t)b * 2048;
    short* arow = A + (size_t)b * KA;
    __shared__ float se[2048];
    __shared__ short sebf[2048];
    int t = threadIdx.x;

    float4 v0 = ((const float4*)e)[t * 2];
    float4 v1 = ((const float4*)e)[t * 2 + 1];
    ((float4*)se)[t * 2] = v0;
    ((float4*)se)[t * 2 + 1] = v1;
    short8v sb;
    sb[0] = f2bf(v0.x); sb[1] = f2bf(v0.y); sb[2] = f2bf(v0.z); sb[3] = f2bf(v0.w);
    sb[4] = f2bf(v1.x); sb[5] = f2bf(v1.y); sb[6] = f2bf(v1.z); sb[7] = f2bf(v1.w);
    ((short8v*)sebf)[t] = sb;
    *(short8v*)&arow[t * 8] = sb;   // E segment [0, 2048)

    __syncthreads();
    if (t < 64) {
        float s = 0.f;
        #pragma unroll
        for (int f = 0; f < 32; ++f) s += se[f * 64 + t];
        FS[(size_t)b * 64 + t] = f2bf(s);
    }

    // G = E E^T via MFMA: 4 waves, one 16x16 tile each, K=64 in 2 steps
    int wid = t >> 6, lane = t & 63;
    int tm = wid >> 1, tn = wid & 1;
    int lr = lane & 15, lk = (lane >> 4) * 8;
    f32x4 g = {0.f, 0.f, 0.f, 0.f};
    #pragma unroll
    for (int ks = 0; ks < 2; ++ks) {
        short8v a  = *(const short8v*)&sebf[(tm * 16 + lr) * 64 + ks * 32 + lk];
        short8v bb = *(const short8v*)&sebf[(tn * 16 + lr) * 64 + ks * 32 + lk];
        g = __builtin_amdgcn_mfma_f32_16x16x32_bf16(a, bb, g, 0, 0, 0);
    }
    #pragma unroll
    for (int r = 0; r < 4; ++r) {
        int grow = tm * 16 + (lane >> 4) * 4 + r;
        int gcol = tn * 16 + lr;
        arow[2048 + grow * 32 + gcol] = f2bf(g[r]);  // G segment [2048, 3072)
    }
}

// ---------------- prep W: one block per unit u ----------------
__global__ __launch_bounds__(256) void prep_w(const float* __restrict__ lw,
                                              const float* __restrict__ iw,
                                              const float* __restrict__ ow,
                                              short* __restrict__ Wt) {
    int u = blockIdx.x;
    int t = threadIdx.x;
    short* w = Wt + (size_t)u * KW;

    for (int k = t; k < 2048; k += 256) w[k] = f2bf(lw[(size_t)k * 256 + u]);

    __shared__ float wi[32];
    if (t < 32) wi[t] = iw[u * 32 + t];
    __syncthreads();
    for (int idx = t; idx < 1024; idx += 256)
        w[2048 + idx] = f2bf(wi[idx >> 5] * wi[idx & 31]);

    const float* owu = ow + (size_t)u * 4096;
    for (int i = t; i < 512; i += 256) {
        float4 a = ((const float4*)owu)[i * 2];
        float4 b = ((const float4*)owu)[i * 2 + 1];
        short8v s;
        s[0] = f2bf(a.x); s[1] = f2bf(a.y); s[2] = f2bf(a.z); s[3] = f2bf(a.w);
        s[4] = f2bf(b.x); s[5] = f2bf(b.y); s[6] = f2bf(b.z); s[7] = f2bf(b.w);
        *(short8v*)&w[3072 + i * 8] = s;
    }
}

// ---------------- GEMM v5 ----------------
// 512 blocks: id -> mt(16) x nt(4) x c8(8). c8: 0-1 seg0 (K-chunk 1024), 2-3 seg1
// (chunk 512), 4-7 seg2 (chunk 1024, A generated from FS). 4 waves, wave = 64x64.
__global__ __launch_bounds__(256) void gemm_tile(const short* __restrict__ A,
                                                 const short* __restrict__ Wt,
                                                 const short* __restrict__ FS,
                                                 float* __restrict__ out) {
    __shared__ short As[2][16384];   // 64 KB (seg2: As[0] = fs tile 256x64)
    __shared__ short Bs[2][4096];    // 16 KB

    int id = blockIdx.x;
    int mt = id >> 5, r5 = id & 31, nt = r5 >> 3, c8 = r5 & 7;
    int seg, kc;
    if (c8 < 2)      { seg = 0; kc = c8; }
    else if (c8 < 4) { seg = 1; kc = c8 - 2; }
    else             { seg = 2; kc = c8 - 4; }
    const int nk = (seg == 1) ? 8 : 16;
    int brow = mt * 256, bcol = nt * 64;
    int akoff = (seg == 0) ? kc * 1024 : 2048 + kc * 512;
    int boff  = (seg == 0) ? kc * 1024 : (seg == 1) ? 2048 + kc * 512 : 3072 + kc * 1024;

    int t = threadIdx.x, w = t >> 6, lane = t & 63;
    int lr = lane & 15, hi = lane >> 4;
    int srow = t >> 3;                       // staging row 0..31 per issue
    int soct = (t & 7) ^ (srow & 7);         // pre-swizzled source octet (involution)

    const short* Asrc = A  + (size_t)(brow + srow) * KA + akoff + soct * 8;
    const short* Bsrc = Wt + (size_t)(bcol + srow) * KW + boff  + soct * 8;
    const short* Fsrc = FS + (size_t)(brow + srow) * 64 + soct * 8;

    auto stageA = [&](int p, int kt) {
        #pragma unroll
        for (int i = 0; i < 8; ++i)
            GLOAD(Asrc + (size_t)i * 32 * KA + kt * 64, &As[p][i * 2048 + t * 8]);
    };
    auto stageB = [&](int p, int kt) {
        #pragma unroll
        for (int i = 0; i < 2; ++i)
            GLOAD(Bsrc + (size_t)i * 32 * KW + kt * 64, &Bs[p][i * 2048 + t * 8]);
    };

    f32x4 acc[4][4];
    #pragma unroll
    for (int m = 0; m < 4; ++m)
        #pragma unroll
        for (int n = 0; n < 4; ++n) acc[m][n] = (f32x4){0.f, 0.f, 0.f, 0.f};

    if (seg == 2) {
        #pragma unroll
        for (int i = 0; i < 8; ++i)          // fs tile, staged once (swizzled)
            GLOAD(Fsrc + (size_t)i * 32 * 64, &As[0][i * 2048 + t * 8]);
        stageB(0, 0);
    } else {
        stageA(0, 0); stageB(0, 0);
    }
    __syncthreads();

    if (seg != 2) {
        for (int kt = 0; kt < nk; ++kt) {
            int cur = kt & 1;
            if (kt + 1 < nk) { stageA(cur ^ 1, kt + 1); stageB(cur ^ 1, kt + 1); }
            #pragma unroll
            for (int ks = 0; ks < 2; ++ks) {
                int oct = ((ks * 4 + hi) ^ (lr & 7)) * 8;   // swizzled read octet
                short8v a[4], b[4];
                #pragma unroll
                for (int m = 0; m < 4; ++m)
                    a[m] = *(const short8v*)&As[cur][(w * 64 + m * 16 + lr) * 64 + oct];
                #pragma unroll
                for (int n = 0; n < 4; ++n)
                    b[n] = *(const short8v*)&Bs[cur][(n * 16 + lr) * 64 + oct];
                #pragma unroll
                for (int m = 0; m < 4; ++m)
                    #pragma unroll
                    for (int n = 0; n < 4; ++n)
                        acc[m][n] = __builtin_amdgcn_mfma_f32_16x16x32_bf16(a[m], b[n], acc[m][n], 0, 0, 0);
            }
            __syncthreads();
        }
    } else {
        // preload the wave's fs j-octets (fixed per lane), f32
        float fj[4][2][8];
        #pragma unroll
        for (int m = 0; m < 4; ++m)
            #pragma unroll
            for (int ks = 0; ks < 2; ++ks) {
                int oct = ((ks * 4 + hi) ^ (lr & 7)) * 8;
                short8v v = *(const short8v*)&As[0][(w * 64 + m * 16 + lr) * 64 + oct];
                #pragma unroll
                for (int e = 0; e < 8; ++e) fj[m][ks][e] = bf2f(v[e]);
            }
        for (int kt = 0; kt < nk; ++kt) {
            int cur = kt & 1;
            if (kt + 1 < nk) stageB(cur ^ 1, kt + 1);
            int iidx = kc * 16 + kt;                 // rank-1 column index 0..63
            int ioff = ((iidx >> 3) ^ (lr & 7)) * 8 + (iidx & 7);
            float s[4];
            #pragma unroll
            for (int m = 0; m < 4; ++m)
                s[m] = bf2f(As[0][(w * 64 + m * 16 + lr) * 64 + ioff]);
            #pragma unroll
            for (int ks = 0; ks < 2; ++ks) {
                int oct = ((ks * 4 + hi) ^ (lr & 7)) * 8;
                short8v b[4];
                #pragma unroll
                for (int n = 0; n < 4; ++n)
                    b[n] = *(const short8v*)&Bs[cur][(n * 16 + lr) * 64 + oct];
                #pragma unroll
                for (int m = 0; m < 4; ++m) {
                    union { int i32[4]; short8v v; } fa;
                    #pragma unroll
                    for (int q = 0; q < 4; ++q)
                        fa.i32[q] = cvtpk(s[m] * fj[m][ks][2 * q], s[m] * fj[m][ks][2 * q + 1]);
                    #pragma unroll
                    for (int n = 0; n < 4; ++n)
                        acc[m][n] = __builtin_amdgcn_mfma_f32_16x16x32_bf16(fa.v, b[n], acc[m][n], 0, 0, 0);
                }
            }
            __syncthreads();
        }
    }

    int segbase = seg * 256;
    #pragma unroll
    for (int m = 0; m < 4; ++m) {
        int row0 = brow + w * 64 + m * 16 + hi * 4;
        #pragma unroll
        for (int n = 0; n < 4; ++n) {
            int col = segbase + bcol + n * 16 + lr;
            #pragma unroll
            for (int r = 0; r < 4; ++r)
                unsafeAtomicAdd(&out[(size_t)(row0 + r) * 768 + col], acc[m][n][r]);
        }
    }
}

extern "C" void kernel_launch(void* const* d_in, const int* in_sizes, int n_in,
                              void* d_out, int out_size, void* d_ws, size_t ws_size,
                              hipStream_t stream) {
    const float* embeds = (const float*)d_in[0];
    const float* lw = (const float*)d_in[1];
    const float* iw = (const float*)d_in[2];
    const float* ow = (const float*)d_in[3];
    float* out = (float*)d_out;

    short* A  = (short*)d_ws;                    // 4096*3072*2 = 25,165,824 B
    short* Wt = A + (size_t)4096 * KA;           // + 256*7168*2 = 3,670,016 B
    short* FS = Wt + (size_t)256 * KW;           // + 4096*64*2 =    524,288 B

    hipMemsetAsync(out, 0, (size_t)out_size * sizeof(float), stream);
    prep_a<<<dim3(4096), dim3(256), 0, stream>>>(embeds, A, FS);
    prep_w<<<dim3(256), dim3(256), 0, stream>>>(lw, iw, ow, Wt);
    gemm_tile<<<dim3(512), dim3(256), 0, stream>>>(A, Wt, FS, out);
}

// Round 6
// 64.706 us; speedup vs baseline: 2.1619x; 1.0078x over previous
//
#include <hip/hip_runtime.h>
#include <hip/hip_bf16.h>

// ProductLayer: B=4096, F=32, D=64, U=256
// out[:,   0:256] = lz       = E[B,2048] @ W1[2048,256]
// out[:, 256:512] = lp_inner = G[B,1024] @ V [1024,256]   (G_b = E_b E_b^T gram)
// out[:, 512:768] = lp_outer = M[B,4096] @ W2[4096,256]   (M rank-1 from FS, in-register)
// A = [E | G] bf16 [4096, 3072]; FS bf16 [4096,64]; Wt bf16 [256, 7168] (N-major)
// GEMM v5: BM=256 BN=64 BK=64, wave=64x64, 512 blocks (2/CU), XOR-swizzled LDS
// (pre-swizzled global src + swizzled ds_read), dbuf stage-first pipeline,
// fp32 atomic epilogue. v6: custom zero kernel (rocclr fill was 41.7us @ 302 GB/s).

#define KA 3072
#define KW 7168

typedef __attribute__((ext_vector_type(8))) short short8v;
typedef __attribute__((ext_vector_type(4))) float f32x4;

#define GLOAD(src, dst) __builtin_amdgcn_global_load_lds( \
    (const __attribute__((address_space(1))) void*)(src), \
    (__attribute__((address_space(3))) void*)(dst), 16, 0, 0)

static __device__ __forceinline__ short f2bf(float f) {
    union { float f; unsigned u; } v; v.f = f;
    unsigned r = v.u + 0x7fffu + ((v.u >> 16) & 1u);  // RNE
    return (short)(r >> 16);
}
static __device__ __forceinline__ float bf2f(short s) {
    union { unsigned u; float f; } v; v.u = ((unsigned)(unsigned short)s) << 16;
    return v.f;
}
static __device__ __forceinline__ int cvtpk(float lo, float hi) {
    int r;
    asm("v_cvt_pk_bf16_f32 %0, %1, %2" : "=v"(r) : "v"(lo), "v"(hi));
    return r;
}

// ---------------- zero out: 4096*768 floats = 786432 float4 ----------------
__global__ __launch_bounds__(256) void zero_out(float4* __restrict__ out) {
    size_t i = (size_t)blockIdx.x * 256 + threadIdx.x;
    #pragma unroll
    for (int r = 0; r < 3; ++r)
        out[i + (size_t)r * 262144] = (float4){0.f, 0.f, 0.f, 0.f};
}

// ---------------- prep A: one block per batch row ----------------
__global__ __launch_bounds__(256) void prep_a(const float* __restrict__ embeds,
                                              short* __restrict__ A,
                                              short* __restrict__ FS) {
    int b = blockIdx.x;
    const float* e = embeds + (size_t)b * 2048;
    short* arow = A + (size_t)b * KA;
    __shared__ float se[2048];
    __shared__ short sebf[2048];
    int t = threadIdx.x;

    float4 v0 = ((const float4*)e)[t * 2];
    float4 v1 = ((const float4*)e)[t * 2 + 1];
    ((float4*)se)[t * 2] = v0;
    ((float4*)se)[t * 2 + 1] = v1;
    short8v sb;
    sb[0] = f2bf(v0.x); sb[1] = f2bf(v0.y); sb[2] = f2bf(v0.z); sb[3] = f2bf(v0.w);
    sb[4] = f2bf(v1.x); sb[5] = f2bf(v1.y); sb[6] = f2bf(v1.z); sb[7] = f2bf(v1.w);
    ((short8v*)sebf)[t] = sb;
    *(short8v*)&arow[t * 8] = sb;   // E segment [0, 2048)

    __syncthreads();
    if (t < 64) {
        float s = 0.f;
        #pragma unroll
        for (int f = 0; f < 32; ++f) s += se[f * 64 + t];
        FS[(size_t)b * 64 + t] = f2bf(s);
    }

    // G = E E^T via MFMA: 4 waves, one 16x16 tile each, K=64 in 2 steps
    int wid = t >> 6, lane = t & 63;
    int tm = wid >> 1, tn = wid & 1;
    int lr = lane & 15, lk = (lane >> 4) * 8;
    f32x4 g = {0.f, 0.f, 0.f, 0.f};
    #pragma unroll
    for (int ks = 0; ks < 2; ++ks) {
        short8v a  = *(const short8v*)&sebf[(tm * 16 + lr) * 64 + ks * 32 + lk];
        short8v bb = *(const short8v*)&sebf[(tn * 16 + lr) * 64 + ks * 32 + lk];
        g = __builtin_amdgcn_mfma_f32_16x16x32_bf16(a, bb, g, 0, 0, 0);
    }
    #pragma unroll
    for (int r = 0; r < 4; ++r) {
        int grow = tm * 16 + (lane >> 4) * 4 + r;
        int gcol = tn * 16 + lr;
        arow[2048 + grow * 32 + gcol] = f2bf(g[r]);  // G segment [2048, 3072)
    }
}

// ---------------- prep W: one block per unit u ----------------
__global__ __launch_bounds__(256) void prep_w(const float* __restrict__ lw,
                                              const float* __restrict__ iw,
                                              const float* __restrict__ ow,
                                              short* __restrict__ Wt) {
    int u = blockIdx.x;
    int t = threadIdx.x;
    short* w = Wt + (size_t)u * KW;

    for (int k = t; k < 2048; k += 256) w[k] = f2bf(lw[(size_t)k * 256 + u]);

    __shared__ float wi[32];
    if (t < 32) wi[t] = iw[u * 32 + t];
    __syncthreads();
    for (int idx = t; idx < 1024; idx += 256)
        w[2048 + idx] = f2bf(wi[idx >> 5] * wi[idx & 31]);

    const float* owu = ow + (size_t)u * 4096;
    for (int i = t; i < 512; i += 256) {
        float4 a = ((const float4*)owu)[i * 2];
        float4 b = ((const float4*)owu)[i * 2 + 1];
        short8v s;
        s[0] = f2bf(a.x); s[1] = f2bf(a.y); s[2] = f2bf(a.z); s[3] = f2bf(a.w);
        s[4] = f2bf(b.x); s[5] = f2bf(b.y); s[6] = f2bf(b.z); s[7] = f2bf(b.w);
        *(short8v*)&w[3072 + i * 8] = s;
    }
}

// ---------------- GEMM v5 ----------------
// 512 blocks: id -> mt(16) x nt(4) x c8(8). c8: 0-1 seg0 (K-chunk 1024), 2-3 seg1
// (chunk 512), 4-7 seg2 (chunk 1024, A generated from FS). 4 waves, wave = 64x64.
__global__ __launch_bounds__(256) void gemm_tile(const short* __restrict__ A,
                                                 const short* __restrict__ Wt,
                                                 const short* __restrict__ FS,
                                                 float* __restrict__ out) {
    __shared__ short As[2][16384];   // 64 KB (seg2: As[0] = fs tile 256x64)
    __shared__ short Bs[2][4096];    // 16 KB

    int id = blockIdx.x;
    int mt = id >> 5, r5 = id & 31, nt = r5 >> 3, c8 = r5 & 7;
    int seg, kc;
    if (c8 < 2)      { seg = 0; kc = c8; }
    else if (c8 < 4) { seg = 1; kc = c8 - 2; }
    else             { seg = 2; kc = c8 - 4; }
    const int nk = (seg == 1) ? 8 : 16;
    int brow = mt * 256, bcol = nt * 64;
    int akoff = (seg == 0) ? kc * 1024 : 2048 + kc * 512;
    int boff  = (seg == 0) ? kc * 1024 : (seg == 1) ? 2048 + kc * 512 : 3072 + kc * 1024;

    int t = threadIdx.x, w = t >> 6, lane = t & 63;
    int lr = lane & 15, hi = lane >> 4;
    int srow = t >> 3;                       // staging row 0..31 per issue
    int soct = (t & 7) ^ (srow & 7);         // pre-swizzled source octet (involution)

    const short* Asrc = A  + (size_t)(brow + srow) * KA + akoff + soct * 8;
    const short* Bsrc = Wt + (size_t)(bcol + srow) * KW + boff  + soct * 8;
    const short* Fsrc = FS + (size_t)(brow + srow) * 64 + soct * 8;

    auto stageA = [&](int p, int kt) {
        #pragma unroll
        for (int i = 0; i < 8; ++i)
            GLOAD(Asrc + (size_t)i * 32 * KA + kt * 64, &As[p][i * 2048 + t * 8]);
    };
    auto stageB = [&](int p, int kt) {
        #pragma unroll
        for (int i = 0; i < 2; ++i)
            GLOAD(Bsrc + (size_t)i * 32 * KW + kt * 64, &Bs[p][i * 2048 + t * 8]);
    };

    f32x4 acc[4][4];
    #pragma unroll
    for (int m = 0; m < 4; ++m)
        #pragma unroll
        for (int n = 0; n < 4; ++n) acc[m][n] = (f32x4){0.f, 0.f, 0.f, 0.f};

    if (seg == 2) {
        #pragma unroll
        for (int i = 0; i < 8; ++i)          // fs tile, staged once (swizzled)
            GLOAD(Fsrc + (size_t)i * 32 * 64, &As[0][i * 2048 + t * 8]);
        stageB(0, 0);
    } else {
        stageA(0, 0); stageB(0, 0);
    }
    __syncthreads();

    if (seg != 2) {
        for (int kt = 0; kt < nk; ++kt) {
            int cur = kt & 1;
            if (kt + 1 < nk) { stageA(cur ^ 1, kt + 1); stageB(cur ^ 1, kt + 1); }
            #pragma unroll
            for (int ks = 0; ks < 2; ++ks) {
                int oct = ((ks * 4 + hi) ^ (lr & 7)) * 8;   // swizzled read octet
                short8v a[4], b[4];
                #pragma unroll
                for (int m = 0; m < 4; ++m)
                    a[m] = *(const short8v*)&As[cur][(w * 64 + m * 16 + lr) * 64 + oct];
                #pragma unroll
                for (int n = 0; n < 4; ++n)
                    b[n] = *(const short8v*)&Bs[cur][(n * 16 + lr) * 64 + oct];
                #pragma unroll
                for (int m = 0; m < 4; ++m)
                    #pragma unroll
                    for (int n = 0; n < 4; ++n)
                        acc[m][n] = __builtin_amdgcn_mfma_f32_16x16x32_bf16(a[m], b[n], acc[m][n], 0, 0, 0);
            }
            __syncthreads();
        }
    } else {
        // preload the wave's fs j-octets (fixed per lane), f32
        float fj[4][2][8];
        #pragma unroll
        for (int m = 0; m < 4; ++m)
            #pragma unroll
            for (int ks = 0; ks < 2; ++ks) {
                int oct = ((ks * 4 + hi) ^ (lr & 7)) * 8;
                short8v v = *(const short8v*)&As[0][(w * 64 + m * 16 + lr) * 64 + oct];
                #pragma unroll
                for (int e = 0; e < 8; ++e) fj[m][ks][e] = bf2f(v[e]);
            }
        for (int kt = 0; kt < nk; ++kt) {
            int cur = kt & 1;
            if (kt + 1 < nk) stageB(cur ^ 1, kt + 1);
            int iidx = kc * 16 + kt;                 // rank-1 column index 0..63
            int ioff = ((iidx >> 3) ^ (lr & 7)) * 8 + (iidx & 7);
            float s[4];
            #pragma unroll
            for (int m = 0; m < 4; ++m)
                s[m] = bf2f(As[0][(w * 64 + m * 16 + lr) * 64 + ioff]);
            #pragma unroll
            for (int ks = 0; ks < 2; ++ks) {
                int oct = ((ks * 4 + hi) ^ (lr & 7)) * 8;
                short8v b[4];
                #pragma unroll
                for (int n = 0; n < 4; ++n)
                    b[n] = *(const short8v*)&Bs[cur][(n * 16 + lr) * 64 + oct];
                #pragma unroll
                for (int m = 0; m < 4; ++m) {
                    union { int i32[4]; short8v v; } fa;
                    #pragma unroll
                    for (int q = 0; q < 4; ++q)
                        fa.i32[q] = cvtpk(s[m] * fj[m][ks][2 * q], s[m] * fj[m][ks][2 * q + 1]);
                    #pragma unroll
                    for (int n = 0; n < 4; ++n)
                        acc[m][n] = __builtin_amdgcn_mfma_f32_16x16x32_bf16(fa.v, b[n], acc[m][n], 0, 0, 0);
                }
            }
            __syncthreads();
        }
    }

    int segbase = seg * 256;
    #pragma unroll
    for (int m = 0; m < 4; ++m) {
        int row0 = brow + w * 64 + m * 16 + hi * 4;
        #pragma unroll
        for (int n = 0; n < 4; ++n) {
            int col = segbase + bcol + n * 16 + lr;
            #pragma unroll
            for (int r = 0; r < 4; ++r)
                unsafeAtomicAdd(&out[(size_t)(row0 + r) * 768 + col], acc[m][n][r]);
        }
    }
}

extern "C" void kernel_launch(void* const* d_in, const int* in_sizes, int n_in,
                              void* d_out, int out_size, void* d_ws, size_t ws_size,
                              hipStream_t stream) {
    const float* embeds = (const float*)d_in[0];
    const float* lw = (const float*)d_in[1];
    const float* iw = (const float*)d_in[2];
    const float* ow = (const float*)d_in[3];
    float* out = (float*)d_out;

    short* A  = (short*)d_ws;                    // 4096*3072*2 = 25,165,824 B
    short* Wt = A + (size_t)4096 * KA;           // + 256*7168*2 = 3,670,016 B
    short* FS = Wt + (size_t)256 * KW;           // + 4096*64*2 =    524,288 B

    zero_out<<<dim3(1024), dim3(256), 0, stream>>>((float4*)out);
    prep_a<<<dim3(4096), dim3(256), 0, stream>>>(embeds, A, FS);
    prep_w<<<dim3(256), dim3(256), 0, stream>>>(lw, iw, ow, Wt);
    gemm_tile<<<dim3(512), dim3(256), 0, stream>>>(A, Wt, FS, out);
}